// Round 3
// baseline (3806.644 us; speedup 1.0000x reference)
//
#include <hip/hip_runtime.h>

#define N_ROWS 16384
#define DIM    512
#define K_CODES 8192

#define BM 64
#define BN 128
#define KT 32

// ---------------- Kernel N: numpy-pairwise fp32 row norms ----------------
// Replicates np.sum(v*v, axis=1) for float32 exactly:
// 512 -> 256+256 -> (128+128)+(128+128); 128-block: 8 accumulators r[j] over
// elements j, j+8, ..., j+120 (sequential adds), combined as
// ((r0+r1)+(r2+r3)) + ((r4+r5)+(r6+r7)). Squares rounded before adding.
__device__ __forceinline__ float np_block128_sq(const float* __restrict__ q) {
    float r[8];
    #pragma unroll
    for (int j = 0; j < 8; ++j) r[j] = __fmul_rn(q[j], q[j]);
    for (int i = 8; i < 128; i += 8) {
        #pragma unroll
        for (int j = 0; j < 8; ++j) r[j] = __fadd_rn(r[j], __fmul_rn(q[i + j], q[i + j]));
    }
    return __fadd_rn(__fadd_rn(__fadd_rn(r[0], r[1]), __fadd_rn(r[2], r[3])),
                     __fadd_rn(__fadd_rn(r[4], r[5]), __fadd_rn(r[6], r[7])));
}

__global__ void vq_np_norm_kernel(const float* __restrict__ x, const float* __restrict__ cb,
                                  float* __restrict__ Arow, float* __restrict__ Bcode) {
    int t = blockIdx.x * blockDim.x + threadIdx.x;
    const float* p;
    float* o;
    if (t < N_ROWS) {
        p = x + (size_t)t * DIM;  o = Arow + t;
    } else if (t < N_ROWS + K_CODES) {
        int j = t - N_ROWS;
        p = cb + (size_t)j * DIM; o = Bcode + j;
    } else return;
    float b0 = np_block128_sq(p);
    float b1 = np_block128_sq(p + 128);
    float b2 = np_block128_sq(p + 256);
    float b3 = np_block128_sq(p + 384);
    *o = __fadd_rn(__fadd_rn(b0, b1), __fadd_rn(b2, b3));
}

// ---------------- Kernel B: tiled argmin, np-float32 dist semantics ----------------
// dist32 = fl32( fl32(A_i + b_j) - 2*fl32(dot_ij) ), argmin lowest-index ties.
__device__ __forceinline__ bool vq_less(float av, int ai, float bv, int bi) {
    return (av < bv) || (av == bv && ai < bi);
}

__launch_bounds__(512)
__global__ void vq_argmin_kernel(const float* __restrict__ x,
                                 const float* __restrict__ cb,
                                 const float* __restrict__ Arow,
                                 const float* __restrict__ Bcode,
                                 int* __restrict__ outIdx) {
    __shared__ __align__(16) float As[KT][BM];
    __shared__ __align__(16) float Bs[KT][BN];

    const int t  = threadIdx.x;
    const int tx = t & 31;   // code group (0..31) -> 4 codes each
    const int ty = t >> 5;   // row group  (0..15) -> 4 rows each
    const int rowBase = blockIdx.x * BM;

    float Ai[4];
    #pragma unroll
    for (int i = 0; i < 4; ++i) Ai[i] = Arow[rowBase + ty * 4 + i];

    float m1v[4];
    int   m1i[4];
    #pragma unroll
    for (int i = 0; i < 4; ++i) { m1v[i] = 3.4e38f; m1i[i] = 0x7FFFFFFF; }

    for (int ct = 0; ct < K_CODES / BN; ++ct) {
        double accd[4][4];
        #pragma unroll
        for (int i = 0; i < 4; ++i)
            #pragma unroll
            for (int j = 0; j < 4; ++j) accd[i][j] = 0.0;

        for (int kt = 0; kt < DIM / KT; ++kt) {
            __syncthreads();
            {   // stage A: 64 rows x 32 k = 512 float4, one per thread
                int row = t >> 3, kq = t & 7;
                float4 v = *(const float4*)(x + (size_t)(rowBase + row) * DIM + kt * KT + kq * 4);
                As[kq*4+0][row] = v.x; As[kq*4+1][row] = v.y;
                As[kq*4+2][row] = v.z; As[kq*4+3][row] = v.w;
            }
            #pragma unroll
            for (int rep = 0; rep < 2; ++rep) {  // stage B: 128 codes x 32 k
                int u = t + rep * 512;
                int row = u >> 3, kq = u & 7;
                float4 v = *(const float4*)(cb + (size_t)(ct * BN + row) * DIM + kt * KT + kq * 4);
                Bs[kq*4+0][row] = v.x; Bs[kq*4+1][row] = v.y;
                Bs[kq*4+2][row] = v.z; Bs[kq*4+3][row] = v.w;
            }
            __syncthreads();

            float acc[4][4];
            #pragma unroll
            for (int i = 0; i < 4; ++i)
                #pragma unroll
                for (int j = 0; j < 4; ++j) acc[i][j] = 0.0f;

            #pragma unroll
            for (int kk = 0; kk < KT; ++kk) {
                float4 a = *(const float4*)&As[kk][ty * 4];
                float4 b = *(const float4*)&Bs[kk][tx * 4];
                acc[0][0] += a.x * b.x; acc[0][1] += a.x * b.y; acc[0][2] += a.x * b.z; acc[0][3] += a.x * b.w;
                acc[1][0] += a.y * b.x; acc[1][1] += a.y * b.y; acc[1][2] += a.y * b.z; acc[1][3] += a.y * b.w;
                acc[2][0] += a.z * b.x; acc[2][1] += a.z * b.y; acc[2][2] += a.z * b.z; acc[2][3] += a.z * b.w;
                acc[3][0] += a.w * b.x; acc[3][1] += a.w * b.y; acc[3][2] += a.w * b.z; acc[3][3] += a.w * b.w;
            }
            #pragma unroll
            for (int i = 0; i < 4; ++i)
                #pragma unroll
                for (int j = 0; j < 4; ++j) accd[i][j] += (double)acc[i][j];
        }

        // fold 128-code tile with np-fp32 dist formula (codes ascending per lane)
        #pragma unroll
        for (int j = 0; j < 4; ++j) {
            int code = ct * BN + tx * 4 + j;
            float bj = Bcode[code];
            #pragma unroll
            for (int i = 0; i < 4; ++i) {
                float m32 = (float)accd[i][j];
                float tsum = __fadd_rn(Ai[i], bj);
                float dist = __fsub_rn(tsum, 2.0f * m32);
                if (vq_less(dist, code, m1v[i], m1i[i])) { m1v[i] = dist; m1i[i] = code; }
            }
        }
    }

    // lex-min reduce across the 32 tx-lanes (xor<32 stays within the ty group)
    #pragma unroll
    for (int m = 16; m; m >>= 1) {
        #pragma unroll
        for (int i = 0; i < 4; ++i) {
            float ov = __shfl_xor(m1v[i], m);
            int   oi = __shfl_xor(m1i[i], m);
            if (vq_less(ov, oi, m1v[i], m1i[i])) { m1v[i] = ov; m1i[i] = oi; }
        }
    }
    if (tx == 0) {
        #pragma unroll
        for (int i = 0; i < 4; ++i) outIdx[rowBase + ty * 4 + i] = m1i[i];
    }
}

// ---------------- Kernel C: gather + outputs + per-row loss partial ----------------
__global__ void vq_gather_kernel(const float* __restrict__ x,
                                 const float* __restrict__ cb,
                                 const int* __restrict__ idxArr,
                                 float* __restrict__ out0,
                                 float* __restrict__ out3,
                                 float* __restrict__ out4,
                                 float* __restrict__ rowPart) {
    int gw = (blockIdx.x * blockDim.x + threadIdx.x) >> 6;
    int lane = threadIdx.x & 63;
    if (gw >= N_ROWS) return;
    int idx = idxArr[gw];
    const float2* xp = (const float2*)(x  + (size_t)gw * DIM);
    const float2* qp = (const float2*)(cb + (size_t)idx * DIM);
    float2* o0 = (float2*)(out0 + (size_t)gw * DIM);
    float2* o3 = (float2*)(out3 + (size_t)gw * DIM);
    float part = 0.0f;
    #pragma unroll
    for (int r = 0; r < 4; ++r) {
        int e = r * 64 + lane;
        float2 xv = xp[e];
        float2 qv = qp[e];
        float dx = qv.x - xv.x, dy = qv.y - xv.y;
        part += dx * dx + dy * dy;
        float2 o; o.x = xv.x + dx; o.y = xv.y + dy;
        o0[e] = o;
        o3[e] = qv;
    }
    #pragma unroll
    for (int m = 32; m; m >>= 1) part += __shfl_xor(part, m);
    if (lane == 0) {
        rowPart[gw] = part;
        out4[gw] = (float)idx;
    }
}

// ---------------- Kernel D: deterministic loss reduce ----------------
__global__ void vq_loss_kernel(const float* __restrict__ rowPart,
                               float* __restrict__ out1, float* __restrict__ out2) {
    __shared__ float red[256];
    int t = threadIdx.x;
    float s = 0.0f;
    for (int r = t; r < N_ROWS; r += 256) s += rowPart[r];
    red[t] = s;
    __syncthreads();
    #pragma unroll
    for (int m = 128; m; m >>= 1) {
        if (t < m) red[t] += red[t + m];
        __syncthreads();
    }
    if (t == 0) {
        float loss = red[0] / (float)(N_ROWS * DIM);
        out1[0] = loss;
        out2[0] = loss;
    }
}

extern "C" void kernel_launch(void* const* d_in, const int* in_sizes, int n_in,
                              void* d_out, int out_size, void* d_ws, size_t ws_size,
                              hipStream_t stream) {
    const float* x  = (const float*)d_in[0];   // [16384, 512]
    const float* cb = (const float*)d_in[1];   // [8192, 512]
    float* out  = (float*)d_out;
    float* out0 = out;                         // quantized_out [8388608]
    float* out1 = out + 8388608;               // q_latent_loss [1]
    float* out2 = out + 8388609;               // e_latent_loss [1]
    float* out3 = out + 8388610;               // quantized [8388608]
    float* out4 = out + 16777218;              // idx as float [16384]

    char* ws = (char*)d_ws;
    float* wsA    = (float*)ws;                    // 16384 floats (np ||x||^2)
    float* wsB    = (float*)(ws + 65536);          // 8192 floats  (np ||e||^2)
    int*   wsIdx  = (int*)(ws + 98304);            // 16384 ints
    float* wsPart = (float*)(ws + 163840);         // 16384 floats

    hipLaunchKernelGGL(vq_np_norm_kernel, dim3(96),  dim3(256), 0, stream, x, cb, wsA, wsB);
    hipLaunchKernelGGL(vq_argmin_kernel,  dim3(N_ROWS / BM), dim3(512), 0, stream,
                       x, cb, wsA, wsB, wsIdx);
    hipLaunchKernelGGL(vq_gather_kernel,  dim3(4096), dim3(256), 0, stream,
                       x, cb, wsIdx, out0, out3, out4, wsPart);
    hipLaunchKernelGGL(vq_loss_kernel,    dim3(1),    dim3(256), 0, stream,
                       wsPart, out1, out2);
}

// Round 4
// 795.809 us; speedup vs baseline: 4.7834x; 4.7834x over previous
//
#include <hip/hip_runtime.h>

typedef unsigned long long u64;
typedef unsigned int u32;
typedef unsigned short u16;

#define N_ROWS 16384
#define DIM    512
#define K_CODES 8192

#define SLICES 4
#define SLICE_CODES 2048
#define BM 128
#define BN 128
#define KC 64
#define CT_TILES (SLICE_CODES / BN)   // 16
#define KSTAGES  (DIM / KC)           // 8

typedef short bf16x8 __attribute__((ext_vector_type(8)));
typedef float f32x4  __attribute__((ext_vector_type(4)));

// LDS plane offsets in ushort units (each plane 128x64 bf16 = 8192 ushorts)
#define LDS_AH 0
#define LDS_AM 8192
#define LDS_BH 16384
#define LDS_BM 24576

__device__ __forceinline__ void t4_insert(u64* a, u64 k) {
    #pragma unroll
    for (int s = 0; s < 4; ++s) {
        u64 o = a[s];
        bool lt = k < o;
        a[s] = lt ? k : o;
        k    = lt ? o : k;
    }
}

// ---------------- Kernel N: numpy-pairwise fp32 row norms (unchanged, passed r3) ----
__device__ __forceinline__ float np_block128_sq(const float* __restrict__ q) {
    float r[8];
    #pragma unroll
    for (int j = 0; j < 8; ++j) r[j] = __fmul_rn(q[j], q[j]);
    for (int i = 8; i < 128; i += 8) {
        #pragma unroll
        for (int j = 0; j < 8; ++j) r[j] = __fadd_rn(r[j], __fmul_rn(q[i + j], q[i + j]));
    }
    return __fadd_rn(__fadd_rn(__fadd_rn(r[0], r[1]), __fadd_rn(r[2], r[3])),
                     __fadd_rn(__fadd_rn(r[4], r[5]), __fadd_rn(r[6], r[7])));
}

__global__ void vq_np_norm_kernel(const float* __restrict__ x, const float* __restrict__ cb,
                                  float* __restrict__ Arow, float* __restrict__ Bcode) {
    int t = blockIdx.x * blockDim.x + threadIdx.x;
    const float* p;
    float* o;
    if (t < N_ROWS) {
        p = x + (size_t)t * DIM;  o = Arow + t;
    } else if (t < N_ROWS + K_CODES) {
        int j = t - N_ROWS;
        p = cb + (size_t)j * DIM; o = Bcode + j;
    } else return;
    float b0 = np_block128_sq(p);
    float b1 = np_block128_sq(p + 128);
    float b2 = np_block128_sq(p + 256);
    float b3 = np_block128_sq(p + 384);
    *o = __fadd_rn(__fadd_rn(b0, b1), __fadd_rn(b2, b3));
}

// ---------------- Kernel S: MFMA screen -> per-row top-4 per code-slice ----------------
// dist_scr = fl32( fl32(A_i + b_j) - 2 * acc ) where acc = hh+hm+mh bf16-split MFMA sum.
// Error ~5e-8 << dist grid (6.1e-5): dist_scr == ref dist32 except ~1e-3/elem breakpoint
// crossings, all absorbed by top-4 + exact refine.
__launch_bounds__(512)
__global__ void vq_screen_kernel(const float* __restrict__ x,
                                 const float* __restrict__ cb,
                                 const float* __restrict__ Arow,
                                 const float* __restrict__ Bcode,
                                 u64* __restrict__ top4out) {
    __shared__ __align__(16) u16 lds[4 * BM * KC];

    const int t = threadIdx.x;
    const int lane = t & 63;
    const int w = t >> 6;         // 0..7
    const int waveM = w >> 1;     // 0..3 -> rows [32*waveM, +32)
    const int waveN = w & 1;      // 0..1 -> cols [64*waveN, +64)
    const int r15 = lane & 15;
    const int g = lane >> 4;      // 0..3

    const int rowBase = blockIdx.x * BM;
    const int slice = blockIdx.y;
    const int sliceBase = slice * SLICE_CODES;

    // preload row norms for this lane's 8 rows
    float Ai[2][4];
    #pragma unroll
    for (int mi = 0; mi < 2; ++mi)
        #pragma unroll
        for (int reg = 0; reg < 4; ++reg)
            Ai[mi][reg] = Arow[rowBase + waveM * 32 + mi * 16 + g * 4 + reg];

    u64 t4[2][4][4];
    #pragma unroll
    for (int mi = 0; mi < 2; ++mi)
        #pragma unroll
        for (int reg = 0; reg < 4; ++reg)
            #pragma unroll
            for (int s = 0; s < 4; ++s) t4[mi][reg][s] = ~0ull;

    for (int ct = 0; ct < CT_TILES; ++ct) {
        f32x4 acc[2][4] = {};

        for (int kt = 0; kt < KSTAGES; ++kt) {
            __syncthreads();
            // ---- stage A: 128 rows x 64 k, bit-truncation bf16 split ----
            #pragma unroll
            for (int i = 0; i < 4; ++i) {
                int u = t + 512 * i;
                int row = u >> 4, k4 = u & 15;
                const float4 v = *(const float4*)(x + (size_t)(rowBase + row) * DIM + kt * KC + k4 * 4);
                u32 b0 = __float_as_uint(v.x), b1 = __float_as_uint(v.y),
                    b2 = __float_as_uint(v.z), b3 = __float_as_uint(v.w);
                u16 h0 = (u16)(b0 >> 16), h1 = (u16)(b1 >> 16), h2 = (u16)(b2 >> 16), h3 = (u16)(b3 >> 16);
                u16 m0 = (u16)(__float_as_uint(v.x - __uint_as_float(b0 & 0xFFFF0000u)) >> 16);
                u16 m1 = (u16)(__float_as_uint(v.y - __uint_as_float(b1 & 0xFFFF0000u)) >> 16);
                u16 m2 = (u16)(__float_as_uint(v.z - __uint_as_float(b2 & 0xFFFF0000u)) >> 16);
                u16 m3 = (u16)(__float_as_uint(v.w - __uint_as_float(b3 & 0xFFFF0000u)) >> 16);
                int idx = (row * 64 + k4 * 4) ^ ((row & 7) << 3);
                *(ushort4*)&lds[LDS_AH + idx] = make_ushort4(h0, h1, h2, h3);
                *(ushort4*)&lds[LDS_AM + idx] = make_ushort4(m0, m1, m2, m3);
            }
            // ---- stage B: 128 codes x 64 k ----
            #pragma unroll
            for (int i = 0; i < 4; ++i) {
                int u = t + 512 * i;
                int row = u >> 4, k4 = u & 15;
                const float4 v = *(const float4*)(cb + (size_t)(sliceBase + ct * BN + row) * DIM + kt * KC + k4 * 4);
                u32 b0 = __float_as_uint(v.x), b1 = __float_as_uint(v.y),
                    b2 = __float_as_uint(v.z), b3 = __float_as_uint(v.w);
                u16 h0 = (u16)(b0 >> 16), h1 = (u16)(b1 >> 16), h2 = (u16)(b2 >> 16), h3 = (u16)(b3 >> 16);
                u16 m0 = (u16)(__float_as_uint(v.x - __uint_as_float(b0 & 0xFFFF0000u)) >> 16);
                u16 m1 = (u16)(__float_as_uint(v.y - __uint_as_float(b1 & 0xFFFF0000u)) >> 16);
                u16 m2 = (u16)(__float_as_uint(v.z - __uint_as_float(b2 & 0xFFFF0000u)) >> 16);
                u16 m3 = (u16)(__float_as_uint(v.w - __uint_as_float(b3 & 0xFFFF0000u)) >> 16);
                int idx = (row * 64 + k4 * 4) ^ ((row & 7) << 3);
                *(ushort4*)&lds[LDS_BH + idx] = make_ushort4(h0, h1, h2, h3);
                *(ushort4*)&lds[LDS_BM + idx] = make_ushort4(m0, m1, m2, m3);
            }
            __syncthreads();

            // ---- MFMA: 2 k-steps of K=32, 3 product passes ----
            #pragma unroll
            for (int ks = 0; ks < 2; ++ks) {
                const int kb = ks * 32 + g * 8;
                bf16x8 Ah[2], Am[2], Bh[4], Bm[4];
                #pragma unroll
                for (int mi = 0; mi < 2; ++mi) {
                    int row = waveM * 32 + mi * 16 + r15;
                    int idx = (row * 64 + kb) ^ ((row & 7) << 3);
                    Ah[mi] = *(const bf16x8*)&lds[LDS_AH + idx];
                    Am[mi] = *(const bf16x8*)&lds[LDS_AM + idx];
                }
                #pragma unroll
                for (int ni = 0; ni < 4; ++ni) {
                    int row = waveN * 64 + ni * 16 + r15;
                    int idx = (row * 64 + kb) ^ ((row & 7) << 3);
                    Bh[ni] = *(const bf16x8*)&lds[LDS_BH + idx];
                    Bm[ni] = *(const bf16x8*)&lds[LDS_BM + idx];
                }
                #pragma unroll
                for (int mi = 0; mi < 2; ++mi)
                    #pragma unroll
                    for (int ni = 0; ni < 4; ++ni) {
                        acc[mi][ni] = __builtin_amdgcn_mfma_f32_16x16x32_bf16(Ah[mi], Bh[ni], acc[mi][ni], 0, 0, 0);
                        acc[mi][ni] = __builtin_amdgcn_mfma_f32_16x16x32_bf16(Ah[mi], Bm[ni], acc[mi][ni], 0, 0, 0);
                        acc[mi][ni] = __builtin_amdgcn_mfma_f32_16x16x32_bf16(Am[mi], Bh[ni], acc[mi][ni], 0, 0, 0);
                    }
            }
        }

        // ---- epilogue: fold this 128-code tile into per-row top-4 ----
        #pragma unroll
        for (int mi = 0; mi < 2; ++mi)
            #pragma unroll
            for (int ni = 0; ni < 4; ++ni) {
                int col = sliceBase + ct * BN + waveN * 64 + ni * 16 + r15;
                float bj = Bcode[col];
                #pragma unroll
                for (int reg = 0; reg < 4; ++reg) {
                    float d = __fsub_rn(__fadd_rn(Ai[mi][reg], bj), 2.0f * acc[mi][ni][reg]);
                    u64 key = ((u64)__float_as_uint(d) << 13) | (u64)(u32)col;
                    t4_insert(t4[mi][reg], key);
                }
            }
    }

    // ---- cross-lane merge over the 16 column-lanes ----
    #pragma unroll
    for (int m = 1; m <= 8; m <<= 1) {
        #pragma unroll
        for (int mi = 0; mi < 2; ++mi)
            #pragma unroll
            for (int reg = 0; reg < 4; ++reg) {
                u64 i0 = __shfl_xor(t4[mi][reg][0], m);
                u64 i1 = __shfl_xor(t4[mi][reg][1], m);
                u64 i2 = __shfl_xor(t4[mi][reg][2], m);
                u64 i3 = __shfl_xor(t4[mi][reg][3], m);
                t4_insert(t4[mi][reg], i0);
                t4_insert(t4[mi][reg], i1);
                t4_insert(t4[mi][reg], i2);
                t4_insert(t4[mi][reg], i3);
            }
    }

    // ---- cross-waveN merge via LDS, then write to ws ----
    __syncthreads();
    u64* t4buf = (u64*)lds;   // [BM][2][4]
    if (r15 == 0) {
        #pragma unroll
        for (int mi = 0; mi < 2; ++mi)
            #pragma unroll
            for (int reg = 0; reg < 4; ++reg) {
                int row = waveM * 32 + mi * 16 + g * 4 + reg;
                #pragma unroll
                for (int s = 0; s < 4; ++s) t4buf[(row * 2 + waveN) * 4 + s] = t4[mi][reg][s];
            }
    }
    __syncthreads();
    if (t < BM) {
        u64 best[4];
        #pragma unroll
        for (int s = 0; s < 4; ++s) best[s] = t4buf[(t * 2 + 0) * 4 + s];
        #pragma unroll
        for (int s = 0; s < 4; ++s) t4_insert(best, t4buf[(t * 2 + 1) * 4 + s]);
        #pragma unroll
        for (int s = 0; s < 4; ++s)
            top4out[((size_t)slice * N_ROWS + rowBase + t) * 4 + s] = best[s];
    }
}

// ---------------- Kernel R: merge slices + exact np-semantics re-decision ----------------
__global__ void vq_refine_kernel(const float* __restrict__ x, const float* __restrict__ cb,
                                 const float* __restrict__ Arow, const float* __restrict__ Bcode,
                                 const u64* __restrict__ top4, int* __restrict__ idxOut,
                                 float* __restrict__ out4) {
    int gw = (blockIdx.x * blockDim.x + threadIdx.x) >> 6;
    int lane = threadIdx.x & 63;
    if (gw >= N_ROWS) return;

    u64 key = ~0ull;
    if (lane < 16) key = top4[((size_t)(lane >> 2) * N_ROWS + gw) * 4 + (lane & 3)];

    u64 cand[4];
    #pragma unroll
    for (int j = 0; j < 4; ++j) {
        u64 mn = key;
        #pragma unroll
        for (int m = 1; m < 64; m <<= 1) { u64 o = __shfl_xor(mn, m); mn = o < mn ? o : mn; }
        cand[j] = mn;
        if (key == mn) key = ~0ull;
    }

    float Ai = Arow[gw];
    const float* xr = x + (size_t)gw * DIM;
    u64 best = ~0ull;
    #pragma unroll
    for (int j = 0; j < 4; ++j) {
        int c = (int)(cand[j] & 8191u);
        const float* er = cb + (size_t)c * DIM;
        double d = 0.0;
        #pragma unroll
        for (int e = 0; e < 8; ++e)
            d = fma((double)xr[e * 64 + lane], (double)er[e * 64 + lane], d);
        #pragma unroll
        for (int m = 1; m < 64; m <<= 1) d += __shfl_xor(d, m);
        float m32 = (float)d;
        float dist = __fsub_rn(__fadd_rn(Ai, Bcode[c]), 2.0f * m32);
        u64 ek = ((u64)__float_as_uint(dist) << 13) | (u64)(u32)c;
        best = ek < best ? ek : best;
    }
    if (lane == 0) {
        int c = (int)(best & 8191u);
        idxOut[gw] = c;
        out4[gw] = (float)c;
    }
}

// ---------------- Kernel C: gather + outputs + per-row loss partial ----------------
__global__ void vq_gather_kernel(const float* __restrict__ x,
                                 const float* __restrict__ cb,
                                 const int* __restrict__ idxArr,
                                 float* __restrict__ out0,
                                 float* __restrict__ out3,
                                 float* __restrict__ rowPart) {
    int gw = (blockIdx.x * blockDim.x + threadIdx.x) >> 6;
    int lane = threadIdx.x & 63;
    if (gw >= N_ROWS) return;
    int idx = idxArr[gw];
    const float2* xp = (const float2*)(x  + (size_t)gw * DIM);
    const float2* qp = (const float2*)(cb + (size_t)idx * DIM);
    float2* o0 = (float2*)(out0 + (size_t)gw * DIM);
    float2* o3 = (float2*)(out3 + (size_t)gw * DIM);
    float part = 0.0f;
    #pragma unroll
    for (int r = 0; r < 4; ++r) {
        int e = r * 64 + lane;
        float2 xv = xp[e];
        float2 qv = qp[e];
        float dx = qv.x - xv.x, dy = qv.y - xv.y;
        part += dx * dx + dy * dy;
        float2 o; o.x = xv.x + dx; o.y = xv.y + dy;
        o0[e] = o;
        o3[e] = qv;
    }
    #pragma unroll
    for (int m = 32; m; m >>= 1) part += __shfl_xor(part, m);
    if (lane == 0) rowPart[gw] = part;
}

// ---------------- Kernel D: deterministic loss reduce ----------------
__global__ void vq_loss_kernel(const float* __restrict__ rowPart,
                               float* __restrict__ out1, float* __restrict__ out2) {
    __shared__ float red[256];
    int t = threadIdx.x;
    float s = 0.0f;
    for (int r = t; r < N_ROWS; r += 256) s += rowPart[r];
    red[t] = s;
    __syncthreads();
    #pragma unroll
    for (int m = 128; m; m >>= 1) {
        if (t < m) red[t] += red[t + m];
        __syncthreads();
    }
    if (t == 0) {
        float loss = red[0] / (float)(N_ROWS * DIM);
        out1[0] = loss;
        out2[0] = loss;
    }
}

extern "C" void kernel_launch(void* const* d_in, const int* in_sizes, int n_in,
                              void* d_out, int out_size, void* d_ws, size_t ws_size,
                              hipStream_t stream) {
    const float* x  = (const float*)d_in[0];   // [16384, 512]
    const float* cb = (const float*)d_in[1];   // [8192, 512]
    float* out  = (float*)d_out;
    float* out0 = out;                         // quantized_out [8388608]
    float* out1 = out + 8388608;               // q_latent_loss [1]
    float* out2 = out + 8388609;               // e_latent_loss [1]
    float* out3 = out + 8388610;               // quantized [8388608]
    float* out4 = out + 16777218;              // idx as float [16384]

    char* ws = (char*)d_ws;
    float* wsA    = (float*)ws;                      // 16384 f      @0
    float* wsB    = (float*)(ws + 65536);            // 8192 f       @64K
    u64*   wsTop4 = (u64*)(ws + 98304);              // 4*16384*4 u64 (2MB)
    int*   wsIdx  = (int*)(ws + 98304 + 2097152);    // 16384 int
    float* wsPart = (float*)(ws + 98304 + 2097152 + 65536); // 16384 f

    hipLaunchKernelGGL(vq_np_norm_kernel, dim3(96), dim3(256), 0, stream, x, cb, wsA, wsB);
    hipLaunchKernelGGL(vq_screen_kernel,  dim3(N_ROWS / BM, SLICES), dim3(512), 0, stream,
                       x, cb, wsA, wsB, wsTop4);
    hipLaunchKernelGGL(vq_refine_kernel,  dim3(4096), dim3(256), 0, stream,
                       x, cb, wsA, wsB, wsTop4, wsIdx, out4);
    hipLaunchKernelGGL(vq_gather_kernel,  dim3(4096), dim3(256), 0, stream,
                       x, cb, wsIdx, out0, out3, wsPart);
    hipLaunchKernelGGL(vq_loss_kernel,    dim3(1),   dim3(256), 0, stream,
                       wsPart, out1, out2);
}

// Round 5
// 678.388 us; speedup vs baseline: 5.6113x; 1.1731x over previous
//
#include <hip/hip_runtime.h>

typedef unsigned long long u64;
typedef unsigned int u32;
typedef unsigned short u16;

#define N_ROWS 16384
#define DIM    512
#define K_CODES 8192

#define SLICES 4
#define SLICE_CODES 2048
#define BM 128
#define BN 128
#define KC 64
#define CT_TILES (SLICE_CODES / BN)   // 16
#define KSTAGES  (DIM / KC)           // 8

typedef short bf16x8 __attribute__((ext_vector_type(8)));
typedef float f32x4  __attribute__((ext_vector_type(4)));

// LDS plane offsets in ushort units (each plane 128x64 bf16 = 8192 ushorts)
#define LDS_AH 0
#define LDS_AM 8192
#define LDS_BH 16384
#define LDS_BM 24576

__device__ __forceinline__ void t2_insert(u64* a, u64 k) {
    u64 lo = a[0], hi = a[1];
    bool lt0 = k < lo;
    u64 n1k = (k < hi) ? k : hi;
    a[0] = lt0 ? k : lo;
    a[1] = lt0 ? lo : n1k;
}

// ---------------- Kernel P: precompute bf16 bit-truncation splits ----------------
// hi = trunc16(x); mid = trunc16(x - hi). Same formula as the (verified) r4
// in-loop split, now done once, memory-bound.
__global__ void vq_split_kernel(const float* __restrict__ x, const float* __restrict__ cb,
                                u16* __restrict__ xhi, u16* __restrict__ xmid,
                                u16* __restrict__ cbhi, u16* __restrict__ cbmid) {
    size_t t = (size_t)blockIdx.x * blockDim.x + threadIdx.x;
    const size_t nx = (size_t)N_ROWS * DIM / 4;   // float4 groups
    const size_t nc = (size_t)K_CODES * DIM / 4;
    const float4* src;
    u16 *hi, *mid;
    size_t off;
    if (t < nx)            { src = (const float4*)x;  hi = xhi;  mid = xmid;  off = t; }
    else if (t < nx + nc)  { src = (const float4*)cb; hi = cbhi; mid = cbmid; off = t - nx; }
    else return;
    float4 v = src[off];
    u32 b0 = __float_as_uint(v.x), b1 = __float_as_uint(v.y),
        b2 = __float_as_uint(v.z), b3 = __float_as_uint(v.w);
    u16 h0 = (u16)(b0 >> 16), h1 = (u16)(b1 >> 16), h2 = (u16)(b2 >> 16), h3 = (u16)(b3 >> 16);
    u16 m0 = (u16)(__float_as_uint(v.x - __uint_as_float(b0 & 0xFFFF0000u)) >> 16);
    u16 m1 = (u16)(__float_as_uint(v.y - __uint_as_float(b1 & 0xFFFF0000u)) >> 16);
    u16 m2 = (u16)(__float_as_uint(v.z - __uint_as_float(b2 & 0xFFFF0000u)) >> 16);
    u16 m3 = (u16)(__float_as_uint(v.w - __uint_as_float(b3 & 0xFFFF0000u)) >> 16);
    ((ushort4*)hi)[off]  = make_ushort4(h0, h1, h2, h3);
    ((ushort4*)mid)[off] = make_ushort4(m0, m1, m2, m3);
}

// ---------------- Kernel N: numpy-pairwise fp32 row norms (verified r3) ----------------
__device__ __forceinline__ float np_block128_sq(const float* __restrict__ q) {
    float r[8];
    #pragma unroll
    for (int j = 0; j < 8; ++j) r[j] = __fmul_rn(q[j], q[j]);
    for (int i = 8; i < 128; i += 8) {
        #pragma unroll
        for (int j = 0; j < 8; ++j) r[j] = __fadd_rn(r[j], __fmul_rn(q[i + j], q[i + j]));
    }
    return __fadd_rn(__fadd_rn(__fadd_rn(r[0], r[1]), __fadd_rn(r[2], r[3])),
                     __fadd_rn(__fadd_rn(r[4], r[5]), __fadd_rn(r[6], r[7])));
}

__global__ void vq_np_norm_kernel(const float* __restrict__ x, const float* __restrict__ cb,
                                  float* __restrict__ Arow, float* __restrict__ Bcode) {
    int t = blockIdx.x * blockDim.x + threadIdx.x;
    const float* p;
    float* o;
    if (t < N_ROWS) {
        p = x + (size_t)t * DIM;  o = Arow + t;
    } else if (t < N_ROWS + K_CODES) {
        int j = t - N_ROWS;
        p = cb + (size_t)j * DIM; o = Bcode + j;
    } else return;
    float b0 = np_block128_sq(p);
    float b1 = np_block128_sq(p + 128);
    float b2 = np_block128_sq(p + 256);
    float b3 = np_block128_sq(p + 384);
    *o = __fadd_rn(__fadd_rn(b0, b1), __fadd_rn(b2, b3));
}

// ---------------- Kernel S: MFMA screen -> per-row top-2 per code-slice ----------------
__launch_bounds__(512)
__global__ void vq_screen_kernel(const u16* __restrict__ xhi, const u16* __restrict__ xmid,
                                 const u16* __restrict__ cbhi, const u16* __restrict__ cbmid,
                                 const float* __restrict__ Arow,
                                 const float* __restrict__ Bcode,
                                 u64* __restrict__ top2out) {
    __shared__ __align__(16) u16 lds[4 * BM * KC];

    const int t = threadIdx.x;
    const int lane = t & 63;
    const int w = t >> 6;         // 0..7
    const int waveM = w >> 1;     // 0..3 -> rows [32*waveM, +32)
    const int waveN = w & 1;      // 0..1 -> cols [64*waveN, +64)
    const int r15 = lane & 15;
    const int g = lane >> 4;      // 0..3

    const int rowBase = blockIdx.x * BM;
    const int slice = blockIdx.y;
    const int sliceBase = slice * SLICE_CODES;

    float Ai[2][4];
    #pragma unroll
    for (int mi = 0; mi < 2; ++mi)
        #pragma unroll
        for (int reg = 0; reg < 4; ++reg)
            Ai[mi][reg] = Arow[rowBase + waveM * 32 + mi * 16 + g * 4 + reg];

    u64 t2[2][4][2];
    #pragma unroll
    for (int mi = 0; mi < 2; ++mi)
        #pragma unroll
        for (int reg = 0; reg < 4; ++reg) { t2[mi][reg][0] = ~0ull; t2[mi][reg][1] = ~0ull; }

    for (int ct = 0; ct < CT_TILES; ++ct) {
        f32x4 acc[2][4] = {};

        for (int kt = 0; kt < KSTAGES; ++kt) {
            __syncthreads();
            // ---- stage A: 128 rows x 64 k, both planes, no conversion ----
            #pragma unroll
            for (int i = 0; i < 2; ++i) {
                int u = t + 512 * i;
                int row = u >> 3, kg = u & 7;
                size_t gidx = (size_t)(rowBase + row) * DIM + kt * KC + kg * 8;
                bf16x8 vh = *(const bf16x8*)(xhi + gidx);
                bf16x8 vm = *(const bf16x8*)(xmid + gidx);
                int idx = (row * 64 + kg * 8) ^ ((row & 7) << 3);
                *(bf16x8*)&lds[LDS_AH + idx] = vh;
                *(bf16x8*)&lds[LDS_AM + idx] = vm;
            }
            // ---- stage B: 128 codes x 64 k ----
            #pragma unroll
            for (int i = 0; i < 2; ++i) {
                int u = t + 512 * i;
                int row = u >> 3, kg = u & 7;
                size_t gidx = (size_t)(sliceBase + ct * BN + row) * DIM + kt * KC + kg * 8;
                bf16x8 vh = *(const bf16x8*)(cbhi + gidx);
                bf16x8 vm = *(const bf16x8*)(cbmid + gidx);
                int idx = (row * 64 + kg * 8) ^ ((row & 7) << 3);
                *(bf16x8*)&lds[LDS_BH + idx] = vh;
                *(bf16x8*)&lds[LDS_BM + idx] = vm;
            }
            __syncthreads();

            #pragma unroll
            for (int ks = 0; ks < 2; ++ks) {
                const int kb = ks * 32 + g * 8;
                bf16x8 Ah[2], Am[2], Bh[4], Bm[4];
                #pragma unroll
                for (int mi = 0; mi < 2; ++mi) {
                    int row = waveM * 32 + mi * 16 + r15;
                    int idx = (row * 64 + kb) ^ ((row & 7) << 3);
                    Ah[mi] = *(const bf16x8*)&lds[LDS_AH + idx];
                    Am[mi] = *(const bf16x8*)&lds[LDS_AM + idx];
                }
                #pragma unroll
                for (int ni = 0; ni < 4; ++ni) {
                    int row = waveN * 64 + ni * 16 + r15;
                    int idx = (row * 64 + kb) ^ ((row & 7) << 3);
                    Bh[ni] = *(const bf16x8*)&lds[LDS_BH + idx];
                    Bm[ni] = *(const bf16x8*)&lds[LDS_BM + idx];
                }
                #pragma unroll
                for (int mi = 0; mi < 2; ++mi)
                    #pragma unroll
                    for (int ni = 0; ni < 4; ++ni) {
                        acc[mi][ni] = __builtin_amdgcn_mfma_f32_16x16x32_bf16(Ah[mi], Bh[ni], acc[mi][ni], 0, 0, 0);
                        acc[mi][ni] = __builtin_amdgcn_mfma_f32_16x16x32_bf16(Ah[mi], Bm[ni], acc[mi][ni], 0, 0, 0);
                        acc[mi][ni] = __builtin_amdgcn_mfma_f32_16x16x32_bf16(Am[mi], Bh[ni], acc[mi][ni], 0, 0, 0);
                    }
            }
        }

        // ---- epilogue: fold 128-code tile into per-row top-2 ----
        float bjv[4];
        #pragma unroll
        for (int ni = 0; ni < 4; ++ni)
            bjv[ni] = Bcode[sliceBase + ct * BN + waveN * 64 + ni * 16 + r15];
        #pragma unroll
        for (int mi = 0; mi < 2; ++mi)
            #pragma unroll
            for (int ni = 0; ni < 4; ++ni) {
                int col = sliceBase + ct * BN + waveN * 64 + ni * 16 + r15;
                #pragma unroll
                for (int reg = 0; reg < 4; ++reg) {
                    float d = __fsub_rn(__fadd_rn(Ai[mi][reg], bjv[ni]), 2.0f * acc[mi][ni][reg]);
                    u64 key = ((u64)__float_as_uint(d) << 13) | (u64)(u32)col;
                    t2_insert(t2[mi][reg], key);
                }
            }
    }

    // ---- cross-lane merge over the 16 column-lanes ----
    #pragma unroll
    for (int m = 1; m <= 8; m <<= 1) {
        #pragma unroll
        for (int mi = 0; mi < 2; ++mi)
            #pragma unroll
            for (int reg = 0; reg < 4; ++reg) {
                u64 i0 = __shfl_xor(t2[mi][reg][0], m);
                u64 i1 = __shfl_xor(t2[mi][reg][1], m);
                t2_insert(t2[mi][reg], i0);
                t2_insert(t2[mi][reg], i1);
            }
    }

    // ---- cross-waveN merge via LDS, then write to ws ----
    __syncthreads();
    u64* t2buf = (u64*)lds;   // [BM][2][2]
    if (r15 == 0) {
        #pragma unroll
        for (int mi = 0; mi < 2; ++mi)
            #pragma unroll
            for (int reg = 0; reg < 4; ++reg) {
                int row = waveM * 32 + mi * 16 + g * 4 + reg;
                t2buf[(row * 2 + waveN) * 2 + 0] = t2[mi][reg][0];
                t2buf[(row * 2 + waveN) * 2 + 1] = t2[mi][reg][1];
            }
    }
    __syncthreads();
    if (t < BM) {
        u64 best[2];
        best[0] = t2buf[(t * 2 + 0) * 2 + 0];
        best[1] = t2buf[(t * 2 + 0) * 2 + 1];
        t2_insert(best, t2buf[(t * 2 + 1) * 2 + 0]);
        t2_insert(best, t2buf[(t * 2 + 1) * 2 + 1]);
        top2out[((size_t)slice * N_ROWS + rowBase + t) * 2 + 0] = best[0];
        top2out[((size_t)slice * N_ROWS + rowBase + t) * 2 + 1] = best[1];
    }
}

// ---------------- Kernel R: exact np-semantics re-decision over 8 candidates ----------------
__global__ void vq_refine_kernel(const float* __restrict__ x, const float* __restrict__ cb,
                                 const float* __restrict__ Arow, const float* __restrict__ Bcode,
                                 const u64* __restrict__ top2, int* __restrict__ idxOut,
                                 float* __restrict__ out4) {
    int gw = (blockIdx.x * blockDim.x + threadIdx.x) >> 6;
    int lane = threadIdx.x & 63;
    if (gw >= N_ROWS) return;

    u64 key = ~0ull;
    if (lane < 8) key = top2[((size_t)(lane >> 1) * N_ROWS + gw) * 2 + (lane & 1)];

    float Ai = Arow[gw];
    const float* xr = x + (size_t)gw * DIM;
    u64 best = ~0ull;
    #pragma unroll
    for (int j = 0; j < 8; ++j) {
        u64 ck = __shfl(key, j);
        int c = (int)(ck & 8191u);
        const float* er = cb + (size_t)c * DIM;
        double d = 0.0;
        #pragma unroll
        for (int e = 0; e < 8; ++e)
            d = fma((double)xr[e * 64 + lane], (double)er[e * 64 + lane], d);
        #pragma unroll
        for (int m = 1; m < 64; m <<= 1) d += __shfl_xor(d, m);
        float m32 = (float)d;
        float dist = __fsub_rn(__fadd_rn(Ai, Bcode[c]), 2.0f * m32);
        u64 ek = ((u64)__float_as_uint(dist) << 13) | (u64)(u32)c;
        best = ek < best ? ek : best;
    }
    if (lane == 0) {
        int c = (int)(best & 8191u);
        idxOut[gw] = c;
        out4[gw] = (float)c;
    }
}

// ---------------- Kernel C: gather + outputs + per-row loss partial ----------------
__global__ void vq_gather_kernel(const float* __restrict__ x,
                                 const float* __restrict__ cb,
                                 const int* __restrict__ idxArr,
                                 float* __restrict__ out0,
                                 float* __restrict__ out3,
                                 float* __restrict__ rowPart) {
    int gw = (blockIdx.x * blockDim.x + threadIdx.x) >> 6;
    int lane = threadIdx.x & 63;
    if (gw >= N_ROWS) return;
    int idx = idxArr[gw];
    const float2* xp = (const float2*)(x  + (size_t)gw * DIM);
    const float2* qp = (const float2*)(cb + (size_t)idx * DIM);
    float2* o0 = (float2*)(out0 + (size_t)gw * DIM);
    float2* o3 = (float2*)(out3 + (size_t)gw * DIM);
    float part = 0.0f;
    #pragma unroll
    for (int r = 0; r < 4; ++r) {
        int e = r * 64 + lane;
        float2 xv = xp[e];
        float2 qv = qp[e];
        float dx = qv.x - xv.x, dy = qv.y - xv.y;
        part += dx * dx + dy * dy;
        float2 o; o.x = xv.x + dx; o.y = xv.y + dy;
        o0[e] = o;
        o3[e] = qv;
    }
    #pragma unroll
    for (int m = 32; m; m >>= 1) part += __shfl_xor(part, m);
    if (lane == 0) rowPart[gw] = part;
}

// ---------------- Kernel D: deterministic loss reduce ----------------
__global__ void vq_loss_kernel(const float* __restrict__ rowPart,
                               float* __restrict__ out1, float* __restrict__ out2) {
    __shared__ float red[256];
    int t = threadIdx.x;
    float s = 0.0f;
    for (int r = t; r < N_ROWS; r += 256) s += rowPart[r];
    red[t] = s;
    __syncthreads();
    #pragma unroll
    for (int m = 128; m; m >>= 1) {
        if (t < m) red[t] += red[t + m];
        __syncthreads();
    }
    if (t == 0) {
        float loss = red[0] / (float)(N_ROWS * DIM);
        out1[0] = loss;
        out2[0] = loss;
    }
}

extern "C" void kernel_launch(void* const* d_in, const int* in_sizes, int n_in,
                              void* d_out, int out_size, void* d_ws, size_t ws_size,
                              hipStream_t stream) {
    const float* x  = (const float*)d_in[0];   // [16384, 512]
    const float* cb = (const float*)d_in[1];   // [8192, 512]
    float* out  = (float*)d_out;
    float* out0 = out;                         // quantized_out [8388608]
    float* out1 = out + 8388608;               // q_latent_loss [1]
    float* out2 = out + 8388609;               // e_latent_loss [1]
    float* out3 = out + 8388610;               // quantized [8388608]
    float* out4 = out + 16777218;              // idx as float [16384]

    // d_out doubles as split scratch until vq_gather overwrites it (stream-ordered):
    // xhi/xmid fill the out0 region exactly; cbhi/cbmid live inside the out3 region
    // at a 16B-aligned offset, ending well before out4.
    u16* xhi   = (u16*)out0;                       // 8.39M u16 = [0, 4194304) floats
    u16* xmid  = (u16*)(out + 4194304);            // [4194304, 8388608)
    u16* cbhi  = (u16*)(out + 8388612);            // [8388612, 10485764)  16B-aligned
    u16* cbmid = (u16*)(out + 10485764);           // [10485764, 12582916)

    char* ws = (char*)d_ws;
    float* wsA    = (float*)ws;                        // 16384 f
    float* wsB    = (float*)(ws + 65536);              // 8192 f
    u64*   wsTop2 = (u64*)(ws + 98304);                // 4*16384*2 u64 = 1MB
    int*   wsIdx  = (int*)(ws + 98304 + 1048576);      // 16384 int
    float* wsPart = (float*)(ws + 98304 + 1048576 + 65536); // 16384 f

    hipLaunchKernelGGL(vq_split_kernel,   dim3(12288), dim3(256), 0, stream,
                       x, cb, xhi, xmid, cbhi, cbmid);
    hipLaunchKernelGGL(vq_np_norm_kernel, dim3(96), dim3(256), 0, stream, x, cb, wsA, wsB);
    hipLaunchKernelGGL(vq_screen_kernel,  dim3(N_ROWS / BM, SLICES), dim3(512), 0, stream,
                       xhi, xmid, cbhi, cbmid, wsA, wsB, wsTop2);
    hipLaunchKernelGGL(vq_refine_kernel,  dim3(4096), dim3(256), 0, stream,
                       x, cb, wsA, wsB, wsTop2, wsIdx, out4);
    hipLaunchKernelGGL(vq_gather_kernel,  dim3(4096), dim3(256), 0, stream,
                       x, cb, wsIdx, out0, out3, wsPart);
    hipLaunchKernelGGL(vq_loss_kernel,    dim3(1),   dim3(256), 0, stream,
                       wsPart, out1, out2);
}

// Round 6
// 577.852 us; speedup vs baseline: 6.5876x; 1.1740x over previous
//
#include <hip/hip_runtime.h>

typedef unsigned long long u64;
typedef unsigned int u32;
typedef unsigned short u16;

#define N_ROWS 16384
#define DIM    512
#define K_CODES 8192

#define SLICES 4
#define SLICE_CODES 2048
#define BM 128
#define BN 128
#define KC 64
#define CT_TILES (SLICE_CODES / BN)   // 16
#define KSTAGES  (DIM / KC)           // 8
#define TOT_STAGES (CT_TILES * KSTAGES)  // 128

typedef short bf16x8 __attribute__((ext_vector_type(8)));
typedef float f32x4  __attribute__((ext_vector_type(4)));

// LDS plane offsets in ushort units (each plane 128x64 bf16 = 8192 ushorts)
#define LDS_AH 0
#define LDS_AM 8192
#define LDS_BH 16384
#define LDS_BM 24576

__device__ __forceinline__ void t2_insert(u64* a, u64 k) {
    u64 lo = a[0], hi = a[1];
    bool lt0 = k < lo;
    u64 n1k = (k < hi) ? k : hi;
    a[0] = lt0 ? k : lo;
    a[1] = lt0 ? lo : n1k;
}

// ---------------- Kernel P: precompute bf16 bit-truncation splits (verified r5) ----
__global__ void vq_split_kernel(const float* __restrict__ x, const float* __restrict__ cb,
                                u16* __restrict__ xhi, u16* __restrict__ xmid,
                                u16* __restrict__ cbhi, u16* __restrict__ cbmid) {
    size_t t = (size_t)blockIdx.x * blockDim.x + threadIdx.x;
    const size_t nx = (size_t)N_ROWS * DIM / 4;   // float4 groups
    const size_t nc = (size_t)K_CODES * DIM / 4;
    const float4* src;
    u16 *hi, *mid;
    size_t off;
    if (t < nx)            { src = (const float4*)x;  hi = xhi;  mid = xmid;  off = t; }
    else if (t < nx + nc)  { src = (const float4*)cb; hi = cbhi; mid = cbmid; off = t - nx; }
    else return;
    float4 v = src[off];
    u32 b0 = __float_as_uint(v.x), b1 = __float_as_uint(v.y),
        b2 = __float_as_uint(v.z), b3 = __float_as_uint(v.w);
    u16 h0 = (u16)(b0 >> 16), h1 = (u16)(b1 >> 16), h2 = (u16)(b2 >> 16), h3 = (u16)(b3 >> 16);
    u16 m0 = (u16)(__float_as_uint(v.x - __uint_as_float(b0 & 0xFFFF0000u)) >> 16);
    u16 m1 = (u16)(__float_as_uint(v.y - __uint_as_float(b1 & 0xFFFF0000u)) >> 16);
    u16 m2 = (u16)(__float_as_uint(v.z - __uint_as_float(b2 & 0xFFFF0000u)) >> 16);
    u16 m3 = (u16)(__float_as_uint(v.w - __uint_as_float(b3 & 0xFFFF0000u)) >> 16);
    ((ushort4*)hi)[off]  = make_ushort4(h0, h1, h2, h3);
    ((ushort4*)mid)[off] = make_ushort4(m0, m1, m2, m3);
}

// ---------------- Kernel N: numpy-pairwise fp32 row norms (verified r3) ----------------
__device__ __forceinline__ float np_block128_sq(const float* __restrict__ q) {
    float r[8];
    #pragma unroll
    for (int j = 0; j < 8; ++j) r[j] = __fmul_rn(q[j], q[j]);
    for (int i = 8; i < 128; i += 8) {
        #pragma unroll
        for (int j = 0; j < 8; ++j) r[j] = __fadd_rn(r[j], __fmul_rn(q[i + j], q[i + j]));
    }
    return __fadd_rn(__fadd_rn(__fadd_rn(r[0], r[1]), __fadd_rn(r[2], r[3])),
                     __fadd_rn(__fadd_rn(r[4], r[5]), __fadd_rn(r[6], r[7])));
}

__global__ void vq_np_norm_kernel(const float* __restrict__ x, const float* __restrict__ cb,
                                  float* __restrict__ Arow, float* __restrict__ Bcode) {
    int t = blockIdx.x * blockDim.x + threadIdx.x;
    const float* p;
    float* o;
    if (t < N_ROWS) {
        p = x + (size_t)t * DIM;  o = Arow + t;
    } else if (t < N_ROWS + K_CODES) {
        int j = t - N_ROWS;
        p = cb + (size_t)j * DIM; o = Bcode + j;
    } else return;
    float b0 = np_block128_sq(p);
    float b1 = np_block128_sq(p + 128);
    float b2 = np_block128_sq(p + 256);
    float b3 = np_block128_sq(p + 384);
    *o = __fadd_rn(__fadd_rn(b0, b1), __fadd_rn(b2, b3));
}

// ---------------- Kernel S: pipelined MFMA screen (2-phase, counted vmcnt) ----------------
// Double-buffered LDS (2x64KB), global_load_lds width 16 with pre-swizzled global
// source (linear LDS dest; read side applies the same XOR involution).
__launch_bounds__(512)
__global__ void vq_screen_kernel(const u16* __restrict__ xhi, const u16* __restrict__ xmid,
                                 const u16* __restrict__ cbhi, const u16* __restrict__ cbmid,
                                 const float* __restrict__ Arow,
                                 const float* __restrict__ Bcode,
                                 u64* __restrict__ top2out) {
    __shared__ __align__(16) u16 lds[2][4 * BM * KC];   // 2 x 64KB

    const int t = threadIdx.x;
    const int lane = t & 63;
    const int w = t >> 6;         // 0..7
    const int waveM = w >> 1;     // 0..3 -> rows [32*waveM, +32)
    const int waveN = w & 1;      // 0..1 -> cols [64*waveN, +64)
    const int r15 = lane & 15;
    const int g = lane >> 4;      // 0..3

    const int rowBase = blockIdx.x * BM;
    const int slice = blockIdx.y;
    const int sliceBase = slice * SLICE_CODES;

    // staging role: plane p (0=AH,1=AM,2=BH,3=BM), row-half h
    const int h = w & 1;
    const int p = w >> 1;
    const u16* gplane = (p == 0) ? xhi : (p == 1) ? xmid : (p == 2) ? cbhi : cbmid;
    // per-lane source offset: row = r0 + (lane>>3), chunk c = (lane&7) ^ ((lane>>3)&7)
    const size_t laneOff = (size_t)(lane >> 3) * DIM + (size_t)(((lane & 7) ^ ((lane >> 3) & 7)) * 8);
    const int lplane = p * 8192 + h * 64 * 64;   // ushort units, wave-uniform

    auto stage = [&](int s2, int cur2) {
        const int ct2 = s2 >> 3, kt2 = s2 & 7;
        size_t gbase;
        if (p < 2) gbase = (size_t)(rowBase + h * 64) * DIM + (size_t)kt2 * KC;
        else       gbase = (size_t)(sliceBase + ct2 * BN + h * 64) * DIM + (size_t)kt2 * KC;
        const u16* gsrc = gplane + gbase + laneOff;
        u16* ldst = &lds[cur2][lplane];
        #pragma unroll
        for (int i = 0; i < 8; ++i) {
            __builtin_amdgcn_global_load_lds(
                (const __attribute__((address_space(1))) u32*)(gsrc + (size_t)i * 8 * DIM),
                (__attribute__((address_space(3))) u32*)(ldst + i * 8 * 64),
                16, 0, 0);
        }
    };

    float Ai[2][4];
    #pragma unroll
    for (int mi = 0; mi < 2; ++mi)
        #pragma unroll
        for (int reg = 0; reg < 4; ++reg)
            Ai[mi][reg] = Arow[rowBase + waveM * 32 + mi * 16 + g * 4 + reg];

    u64 t2[2][4][2];
    #pragma unroll
    for (int mi = 0; mi < 2; ++mi)
        #pragma unroll
        for (int reg = 0; reg < 4; ++reg) { t2[mi][reg][0] = ~0ull; t2[mi][reg][1] = ~0ull; }

    f32x4 acc[2][4] = {};
    int cur = 0;

    stage(0, 0);

    for (int s = 0; s < TOT_STAGES; ++s) {
        const int ct = s >> 3, kt = s & 7;

        float bjv[4];
        if (kt == 7) {
            #pragma unroll
            for (int ni = 0; ni < 4; ++ni)
                bjv[ni] = Bcode[sliceBase + ct * BN + waveN * 64 + ni * 16 + r15];
        }

        if (s + 1 < TOT_STAGES) {
            stage(s + 1, cur ^ 1);
            asm volatile("s_waitcnt vmcnt(8)" ::: "memory");
        } else {
            asm volatile("s_waitcnt vmcnt(0)" ::: "memory");
        }
        asm volatile("s_barrier" ::: "memory");

        u16* L = lds[cur];
        #pragma unroll
        for (int ks = 0; ks < 2; ++ks) {
            const int kb = ks * 32 + g * 8;
            bf16x8 Ah[2], Am[2], Bh[4], Bm[4];
            #pragma unroll
            for (int mi = 0; mi < 2; ++mi) {
                int row = waveM * 32 + mi * 16 + r15;
                int idx = (row * 64 + kb) ^ ((row & 7) << 3);
                Ah[mi] = *(const bf16x8*)&L[LDS_AH + idx];
                Am[mi] = *(const bf16x8*)&L[LDS_AM + idx];
            }
            #pragma unroll
            for (int ni = 0; ni < 4; ++ni) {
                int row = waveN * 64 + ni * 16 + r15;
                int idx = (row * 64 + kb) ^ ((row & 7) << 3);
                Bh[ni] = *(const bf16x8*)&L[LDS_BH + idx];
                Bm[ni] = *(const bf16x8*)&L[LDS_BM + idx];
            }
            __builtin_amdgcn_s_setprio(1);
            #pragma unroll
            for (int mi = 0; mi < 2; ++mi)
                #pragma unroll
                for (int ni = 0; ni < 4; ++ni) {
                    acc[mi][ni] = __builtin_amdgcn_mfma_f32_16x16x32_bf16(Ah[mi], Bh[ni], acc[mi][ni], 0, 0, 0);
                    acc[mi][ni] = __builtin_amdgcn_mfma_f32_16x16x32_bf16(Ah[mi], Bm[ni], acc[mi][ni], 0, 0, 0);
                    acc[mi][ni] = __builtin_amdgcn_mfma_f32_16x16x32_bf16(Am[mi], Bh[ni], acc[mi][ni], 0, 0, 0);
                }
            __builtin_amdgcn_s_setprio(0);
        }

        if (kt == 7) {
            // fold 128-code tile into per-row top-2 (registers only)
            #pragma unroll
            for (int mi = 0; mi < 2; ++mi)
                #pragma unroll
                for (int ni = 0; ni < 4; ++ni) {
                    int col = sliceBase + ct * BN + waveN * 64 + ni * 16 + r15;
                    #pragma unroll
                    for (int reg = 0; reg < 4; ++reg) {
                        float d = __fsub_rn(__fadd_rn(Ai[mi][reg], bjv[ni]), 2.0f * acc[mi][ni][reg]);
                        u64 key = ((u64)__float_as_uint(d) << 13) | (u64)(u32)col;
                        t2_insert(t2[mi][reg], key);
                    }
                    acc[mi][ni] = (f32x4){0.0f, 0.0f, 0.0f, 0.0f};
                }
        }

        asm volatile("s_barrier" ::: "memory");
        cur ^= 1;
    }

    // ---- cross-lane merge over the 16 column-lanes ----
    #pragma unroll
    for (int m = 1; m <= 8; m <<= 1) {
        #pragma unroll
        for (int mi = 0; mi < 2; ++mi)
            #pragma unroll
            for (int reg = 0; reg < 4; ++reg) {
                u64 i0 = __shfl_xor(t2[mi][reg][0], m);
                u64 i1 = __shfl_xor(t2[mi][reg][1], m);
                t2_insert(t2[mi][reg], i0);
                t2_insert(t2[mi][reg], i1);
            }
    }

    // ---- cross-waveN merge via LDS, then write to ws ----
    __syncthreads();
    u64* t2buf = (u64*)&lds[0][0];   // [BM][2][2]
    if (r15 == 0) {
        #pragma unroll
        for (int mi = 0; mi < 2; ++mi)
            #pragma unroll
            for (int reg = 0; reg < 4; ++reg) {
                int row = waveM * 32 + mi * 16 + g * 4 + reg;
                t2buf[(row * 2 + waveN) * 2 + 0] = t2[mi][reg][0];
                t2buf[(row * 2 + waveN) * 2 + 1] = t2[mi][reg][1];
            }
    }
    __syncthreads();
    if (t < BM) {
        u64 best[2];
        best[0] = t2buf[(t * 2 + 0) * 2 + 0];
        best[1] = t2buf[(t * 2 + 0) * 2 + 1];
        t2_insert(best, t2buf[(t * 2 + 1) * 2 + 0]);
        t2_insert(best, t2buf[(t * 2 + 1) * 2 + 1]);
        top2out[((size_t)slice * N_ROWS + rowBase + t) * 2 + 0] = best[0];
        top2out[((size_t)slice * N_ROWS + rowBase + t) * 2 + 1] = best[1];
    }
}

// ---------------- Kernel R: exact np-semantics re-decision over 8 candidates ----------------
__global__ void vq_refine_kernel(const float* __restrict__ x, const float* __restrict__ cb,
                                 const float* __restrict__ Arow, const float* __restrict__ Bcode,
                                 const u64* __restrict__ top2, int* __restrict__ idxOut,
                                 float* __restrict__ out4) {
    int gw = (blockIdx.x * blockDim.x + threadIdx.x) >> 6;
    int lane = threadIdx.x & 63;
    if (gw >= N_ROWS) return;

    u64 key = ~0ull;
    if (lane < 8) key = top2[((size_t)(lane >> 1) * N_ROWS + gw) * 2 + (lane & 1)];

    float Ai = Arow[gw];
    const float* xr = x + (size_t)gw * DIM;
    u64 best = ~0ull;
    #pragma unroll
    for (int j = 0; j < 8; ++j) {
        u64 ck = __shfl(key, j);
        int c = (int)(ck & 8191u);
        const float* er = cb + (size_t)c * DIM;
        double d = 0.0;
        #pragma unroll
        for (int e = 0; e < 8; ++e)
            d = fma((double)xr[e * 64 + lane], (double)er[e * 64 + lane], d);
        #pragma unroll
        for (int m = 1; m < 64; m <<= 1) d += __shfl_xor(d, m);
        float m32 = (float)d;
        float dist = __fsub_rn(__fadd_rn(Ai, Bcode[c]), 2.0f * m32);
        u64 ek = ((u64)__float_as_uint(dist) << 13) | (u64)(u32)c;
        best = ek < best ? ek : best;
    }
    if (lane == 0) {
        int c = (int)(best & 8191u);
        idxOut[gw] = c;
        out4[gw] = (float)c;
    }
}

// ---------------- Kernel C: gather + outputs + per-row loss partial ----------------
__global__ void vq_gather_kernel(const float* __restrict__ x,
                                 const float* __restrict__ cb,
                                 const int* __restrict__ idxArr,
                                 float* __restrict__ out0,
                                 float* __restrict__ out3,
                                 float* __restrict__ rowPart) {
    int gw = (blockIdx.x * blockDim.x + threadIdx.x) >> 6;
    int lane = threadIdx.x & 63;
    if (gw >= N_ROWS) return;
    int idx = idxArr[gw];
    const float2* xp = (const float2*)(x  + (size_t)gw * DIM);
    const float2* qp = (const float2*)(cb + (size_t)idx * DIM);
    float2* o0 = (float2*)(out0 + (size_t)gw * DIM);
    float2* o3 = (float2*)(out3 + (size_t)gw * DIM);
    float part = 0.0f;
    #pragma unroll
    for (int r = 0; r < 4; ++r) {
        int e = r * 64 + lane;
        float2 xv = xp[e];
        float2 qv = qp[e];
        float dx = qv.x - xv.x, dy = qv.y - xv.y;
        part += dx * dx + dy * dy;
        float2 o; o.x = xv.x + dx; o.y = xv.y + dy;
        o0[e] = o;
        o3[e] = qv;
    }
    #pragma unroll
    for (int m = 32; m; m >>= 1) part += __shfl_xor(part, m);
    if (lane == 0) rowPart[gw] = part;
}

// ---------------- Kernel D: deterministic loss reduce ----------------
__global__ void vq_loss_kernel(const float* __restrict__ rowPart,
                               float* __restrict__ out1, float* __restrict__ out2) {
    __shared__ float red[256];
    int t = threadIdx.x;
    float s = 0.0f;
    for (int r = t; r < N_ROWS; r += 256) s += rowPart[r];
    red[t] = s;
    __syncthreads();
    #pragma unroll
    for (int m = 128; m; m >>= 1) {
        if (t < m) red[t] += red[t + m];
        __syncthreads();
    }
    if (t == 0) {
        float loss = red[0] / (float)(N_ROWS * DIM);
        out1[0] = loss;
        out2[0] = loss;
    }
}

extern "C" void kernel_launch(void* const* d_in, const int* in_sizes, int n_in,
                              void* d_out, int out_size, void* d_ws, size_t ws_size,
                              hipStream_t stream) {
    const float* x  = (const float*)d_in[0];   // [16384, 512]
    const float* cb = (const float*)d_in[1];   // [8192, 512]
    float* out  = (float*)d_out;
    float* out0 = out;                         // quantized_out [8388608]
    float* out1 = out + 8388608;               // q_latent_loss [1]
    float* out2 = out + 8388609;               // e_latent_loss [1]
    float* out3 = out + 8388610;               // quantized [8388608]
    float* out4 = out + 16777218;              // idx as float [16384]

    // d_out doubles as split scratch until vq_gather overwrites it (stream-ordered).
    u16* xhi   = (u16*)out0;                       // [0, 4194304) floats
    u16* xmid  = (u16*)(out + 4194304);            // [4194304, 8388608)
    u16* cbhi  = (u16*)(out + 8388612);            // [8388612, 10485764)  16B-aligned
    u16* cbmid = (u16*)(out + 10485764);           // [10485764, 12582916)

    char* ws = (char*)d_ws;
    float* wsA    = (float*)ws;                        // 16384 f
    float* wsB    = (float*)(ws + 65536);              // 8192 f
    u64*   wsTop2 = (u64*)(ws + 98304);                // 4*16384*2 u64 = 1MB
    int*   wsIdx  = (int*)(ws + 98304 + 1048576);      // 16384 int
    float* wsPart = (float*)(ws + 98304 + 1048576 + 65536); // 16384 f

    hipLaunchKernelGGL(vq_split_kernel,   dim3(12288), dim3(256), 0, stream,
                       x, cb, xhi, xmid, cbhi, cbmid);
    hipLaunchKernelGGL(vq_np_norm_kernel, dim3(96), dim3(256), 0, stream, x, cb, wsA, wsB);
    hipLaunchKernelGGL(vq_screen_kernel,  dim3(N_ROWS / BM, SLICES), dim3(512), 0, stream,
                       xhi, xmid, cbhi, cbmid, wsA, wsB, wsTop2);
    hipLaunchKernelGGL(vq_refine_kernel,  dim3(4096), dim3(256), 0, stream,
                       x, cb, wsA, wsB, wsTop2, wsIdx, out4);
    hipLaunchKernelGGL(vq_gather_kernel,  dim3(4096), dim3(256), 0, stream,
                       x, cb, wsIdx, out0, out3, wsPart);
    hipLaunchKernelGGL(vq_loss_kernel,    dim3(1),   dim3(256), 0, stream,
                       wsPart, out1, out2);
}

// Round 7
// 548.649 us; speedup vs baseline: 6.9382x; 1.0532x over previous
//
#include <hip/hip_runtime.h>

typedef unsigned long long u64;
typedef unsigned int u32;
typedef unsigned short u16;

#define N_ROWS 16384
#define DIM    512
#define K_CODES 8192

#define SLICES 4
#define SLICE_CODES 2048
#define BM 128
#define BN 128
#define KC 32
#define CT_TILES (SLICE_CODES / BN)      // 16
#define KSTAGES  (DIM / KC)              // 16
#define TOT_STAGES (CT_TILES * KSTAGES)  // 256

typedef short bf16x8 __attribute__((ext_vector_type(8)));
typedef float f32x4  __attribute__((ext_vector_type(4)));

__device__ __forceinline__ void t2_insert(u64* a, u64 k) {
    u64 lo = a[0], hi = a[1];
    bool lt0 = k < lo;
    u64 n1k = (k < hi) ? k : hi;
    a[0] = lt0 ? k : lo;
    a[1] = lt0 ? lo : n1k;
}

// ---------------- Kernel P: precompute bf16 bit-truncation splits (verified r5) ----
__global__ void vq_split_kernel(const float* __restrict__ x, const float* __restrict__ cb,
                                u16* __restrict__ xhi, u16* __restrict__ xmid,
                                u16* __restrict__ cbhi, u16* __restrict__ cbmid) {
    size_t t = (size_t)blockIdx.x * blockDim.x + threadIdx.x;
    const size_t nx = (size_t)N_ROWS * DIM / 4;   // float4 groups
    const size_t nc = (size_t)K_CODES * DIM / 4;
    const float4* src;
    u16 *hi, *mid;
    size_t off;
    if (t < nx)            { src = (const float4*)x;  hi = xhi;  mid = xmid;  off = t; }
    else if (t < nx + nc)  { src = (const float4*)cb; hi = cbhi; mid = cbmid; off = t - nx; }
    else return;
    float4 v = src[off];
    u32 b0 = __float_as_uint(v.x), b1 = __float_as_uint(v.y),
        b2 = __float_as_uint(v.z), b3 = __float_as_uint(v.w);
    u16 h0 = (u16)(b0 >> 16), h1 = (u16)(b1 >> 16), h2 = (u16)(b2 >> 16), h3 = (u16)(b3 >> 16);
    u16 m0 = (u16)(__float_as_uint(v.x - __uint_as_float(b0 & 0xFFFF0000u)) >> 16);
    u16 m1 = (u16)(__float_as_uint(v.y - __uint_as_float(b1 & 0xFFFF0000u)) >> 16);
    u16 m2 = (u16)(__float_as_uint(v.z - __uint_as_float(b2 & 0xFFFF0000u)) >> 16);
    u16 m3 = (u16)(__float_as_uint(v.w - __uint_as_float(b3 & 0xFFFF0000u)) >> 16);
    ((ushort4*)hi)[off]  = make_ushort4(h0, h1, h2, h3);
    ((ushort4*)mid)[off] = make_ushort4(m0, m1, m2, m3);
}

// ---------------- Kernel N: numpy-pairwise fp32 row norms (verified r3) ----------------
__device__ __forceinline__ float np_block128_sq(const float* __restrict__ q) {
    float r[8];
    #pragma unroll
    for (int j = 0; j < 8; ++j) r[j] = __fmul_rn(q[j], q[j]);
    for (int i = 8; i < 128; i += 8) {
        #pragma unroll
        for (int j = 0; j < 8; ++j) r[j] = __fadd_rn(r[j], __fmul_rn(q[i + j], q[i + j]));
    }
    return __fadd_rn(__fadd_rn(__fadd_rn(r[0], r[1]), __fadd_rn(r[2], r[3])),
                     __fadd_rn(__fadd_rn(r[4], r[5]), __fadd_rn(r[6], r[7])));
}

__global__ void vq_np_norm_kernel(const float* __restrict__ x, const float* __restrict__ cb,
                                  float* __restrict__ Arow, float* __restrict__ Bcode) {
    int t = blockIdx.x * blockDim.x + threadIdx.x;
    const float* p;
    float* o;
    if (t < N_ROWS) {
        p = x + (size_t)t * DIM;  o = Arow + t;
    } else if (t < N_ROWS + K_CODES) {
        int j = t - N_ROWS;
        p = cb + (size_t)j * DIM; o = Bcode + j;
    } else return;
    float b0 = np_block128_sq(p);
    float b1 = np_block128_sq(p + 128);
    float b2 = np_block128_sq(p + 256);
    float b3 = np_block128_sq(p + 384);
    *o = __fadd_rn(__fadd_rn(b0, b1), __fadd_rn(b2, b3));
}

// ---------------- Kernel S: pipelined MFMA screen, 64x64 wave tiles ----------------
// 4 waves (2M x 2N), wave tile 64x64 = 4mi x 4ni of 16x16x32; KC=32; 2x32KB LDS
// double buffer -> 2 blocks/CU. One plane per wave staged by global_load_lds with
// chunk-XOR swizzle c' = c ^ ((row>>1)&3) (balanced banks both sides).
__launch_bounds__(256, 2)
__global__ void vq_screen_kernel(const u16* __restrict__ xhi, const u16* __restrict__ xmid,
                                 const u16* __restrict__ cbhi, const u16* __restrict__ cbmid,
                                 const float* __restrict__ Arow,
                                 const float* __restrict__ Bcode,
                                 u64* __restrict__ top2out) {
    __shared__ __align__(16) u16 lds[2][4 * BM * KC];   // 2 x 32KB (4 planes x 128 x 32)

    const int t = threadIdx.x;
    const int lane = t & 63;
    const int w = t >> 6;         // 0..3
    const int waveM = w >> 1;     // 0..1 -> rows [64*waveM, +64)
    const int waveN = w & 1;      // 0..1 -> cols [64*waveN, +64)
    const int r15 = lane & 15;
    const int g = lane >> 4;      // 0..3 (k-chunk of the MFMA fragment)
    const int cswz = (r15 >> 1) & 3;   // row-dependent chunk XOR (row base mult of 16)

    const int rowBase = blockIdx.x * BM;
    const int slice = blockIdx.y;
    const int sliceBase = slice * SLICE_CODES;

    // staging role: wave w stages plane w (0=AH,1=AM,2=BH,3=BM)
    const u16* gplane = (w == 0) ? xhi : (w == 1) ? xmid : (w == 2) ? cbhi : cbmid;
    // lane -> (row in 16-row group, swizzled source chunk); constant across iters
    const size_t laneOff = (size_t)(lane >> 2) * DIM
                         + (size_t)((((lane & 3) ^ ((lane >> 3) & 3))) * 8);

    auto stage = [&](int s2, int buf) {
        const int ct2 = s2 >> 4, kt2 = s2 & 15;
        size_t gbase;
        if (w < 2) gbase = (size_t)rowBase * DIM + (size_t)kt2 * KC;
        else       gbase = (size_t)(sliceBase + ct2 * BN) * DIM + (size_t)kt2 * KC;
        const u16* gsrc = gplane + gbase + laneOff;
        u16* ldst = &lds[buf][w * 4096];
        #pragma unroll
        for (int i = 0; i < 8; ++i) {
            __builtin_amdgcn_global_load_lds(
                (const __attribute__((address_space(1))) u32*)(gsrc + (size_t)i * 16 * DIM),
                (__attribute__((address_space(3))) u32*)(ldst + i * 512),
                16, 0, 0);
        }
    };

    float Ai[4][4];
    #pragma unroll
    for (int mi = 0; mi < 4; ++mi)
        #pragma unroll
        for (int reg = 0; reg < 4; ++reg)
            Ai[mi][reg] = Arow[rowBase + waveM * 64 + mi * 16 + g * 4 + reg];

    u64 t2[4][4][2];
    #pragma unroll
    for (int mi = 0; mi < 4; ++mi)
        #pragma unroll
        for (int reg = 0; reg < 4; ++reg) { t2[mi][reg][0] = ~0ull; t2[mi][reg][1] = ~0ull; }

    f32x4 acc[4][4] = {};
    int cur = 0;

    stage(0, 0);

    for (int s = 0; s < TOT_STAGES; ++s) {
        const int ct = s >> 4, kt = s & 15;

        if (s + 1 < TOT_STAGES) {
            stage(s + 1, cur ^ 1);
            asm volatile("s_waitcnt vmcnt(8)" ::: "memory");
        } else {
            asm volatile("s_waitcnt vmcnt(0)" ::: "memory");
        }
        asm volatile("s_barrier" ::: "memory");

        u16* L = lds[cur];
        bf16x8 Ah[4], Am[4];
        #pragma unroll
        for (int mi = 0; mi < 4; ++mi) {
            int row = waveM * 64 + mi * 16 + r15;
            int a = row * 32 + (g ^ cswz) * 8;
            Ah[mi] = *(const bf16x8*)&L[0 * 4096 + a];
            Am[mi] = *(const bf16x8*)&L[1 * 4096 + a];
        }
        __builtin_amdgcn_s_setprio(1);
        #pragma unroll
        for (int ni = 0; ni < 4; ++ni) {
            int row = waveN * 64 + ni * 16 + r15;
            int a = row * 32 + (g ^ cswz) * 8;
            bf16x8 Bh = *(const bf16x8*)&L[2 * 4096 + a];
            bf16x8 Bm = *(const bf16x8*)&L[3 * 4096 + a];
            #pragma unroll
            for (int mi = 0; mi < 4; ++mi) {
                acc[mi][ni] = __builtin_amdgcn_mfma_f32_16x16x32_bf16(Ah[mi], Bh, acc[mi][ni], 0, 0, 0);
                acc[mi][ni] = __builtin_amdgcn_mfma_f32_16x16x32_bf16(Ah[mi], Bm, acc[mi][ni], 0, 0, 0);
                acc[mi][ni] = __builtin_amdgcn_mfma_f32_16x16x32_bf16(Am[mi], Bh, acc[mi][ni], 0, 0, 0);
            }
        }
        __builtin_amdgcn_s_setprio(0);

        if (kt == 15) {
            // fold 128-code tile into per-row top-2 (registers only)
            float bjv[4];
            #pragma unroll
            for (int ni = 0; ni < 4; ++ni)
                bjv[ni] = Bcode[sliceBase + ct * BN + waveN * 64 + ni * 16 + r15];
            #pragma unroll
            for (int mi = 0; mi < 4; ++mi)
                #pragma unroll
                for (int ni = 0; ni < 4; ++ni) {
                    int col = sliceBase + ct * BN + waveN * 64 + ni * 16 + r15;
                    #pragma unroll
                    for (int reg = 0; reg < 4; ++reg) {
                        float d = __fsub_rn(__fadd_rn(Ai[mi][reg], bjv[ni]), 2.0f * acc[mi][ni][reg]);
                        u64 key = ((u64)__float_as_uint(d) << 13) | (u64)(u32)col;
                        t2_insert(t2[mi][reg], key);
                    }
                    acc[mi][ni] = (f32x4){0.0f, 0.0f, 0.0f, 0.0f};
                }
        }

        asm volatile("s_barrier" ::: "memory");
        cur ^= 1;
    }

    // ---- cross-lane merge over the 16 column-lanes ----
    #pragma unroll
    for (int m = 1; m <= 8; m <<= 1) {
        #pragma unroll
        for (int mi = 0; mi < 4; ++mi)
            #pragma unroll
            for (int reg = 0; reg < 4; ++reg) {
                u64 i0 = __shfl_xor(t2[mi][reg][0], m);
                u64 i1 = __shfl_xor(t2[mi][reg][1], m);
                t2_insert(t2[mi][reg], i0);
                t2_insert(t2[mi][reg], i1);
            }
    }

    // ---- cross-waveN merge via LDS, then write to ws ----
    __syncthreads();
    u64* t2buf = (u64*)&lds[0][0];   // [BM][2 waveN][2 slots]
    if (r15 == 0) {
        #pragma unroll
        for (int mi = 0; mi < 4; ++mi)
            #pragma unroll
            for (int reg = 0; reg < 4; ++reg) {
                int row = waveM * 64 + mi * 16 + g * 4 + reg;
                t2buf[(row * 2 + waveN) * 2 + 0] = t2[mi][reg][0];
                t2buf[(row * 2 + waveN) * 2 + 1] = t2[mi][reg][1];
            }
    }
    __syncthreads();
    if (t < BM) {
        u64 best[2];
        best[0] = t2buf[(t * 2 + 0) * 2 + 0];
        best[1] = t2buf[(t * 2 + 0) * 2 + 1];
        t2_insert(best, t2buf[(t * 2 + 1) * 2 + 0]);
        t2_insert(best, t2buf[(t * 2 + 1) * 2 + 1]);
        top2out[((size_t)slice * N_ROWS + rowBase + t) * 2 + 0] = best[0];
        top2out[((size_t)slice * N_ROWS + rowBase + t) * 2 + 1] = best[1];
    }
}

// ---------------- Kernel R: exact np-semantics re-decision over 8 candidates ----------------
__global__ void vq_refine_kernel(const float* __restrict__ x, const float* __restrict__ cb,
                                 const float* __restrict__ Arow, const float* __restrict__ Bcode,
                                 const u64* __restrict__ top2, int* __restrict__ idxOut,
                                 float* __restrict__ out4) {
    int gw = (blockIdx.x * blockDim.x + threadIdx.x) >> 6;
    int lane = threadIdx.x & 63;
    if (gw >= N_ROWS) return;

    u64 key = ~0ull;
    if (lane < 8) key = top2[((size_t)(lane >> 1) * N_ROWS + gw) * 2 + (lane & 1)];

    float Ai = Arow[gw];
    const float* xr = x + (size_t)gw * DIM;
    u64 best = ~0ull;
    #pragma unroll
    for (int j = 0; j < 8; ++j) {
        u64 ck = __shfl(key, j);
        int c = (int)(ck & 8191u);
        const float* er = cb + (size_t)c * DIM;
        double d = 0.0;
        #pragma unroll
        for (int e = 0; e < 8; ++e)
            d = fma((double)xr[e * 64 + lane], (double)er[e * 64 + lane], d);
        #pragma unroll
        for (int m = 1; m < 64; m <<= 1) d += __shfl_xor(d, m);
        float m32 = (float)d;
        float dist = __fsub_rn(__fadd_rn(Ai, Bcode[c]), 2.0f * m32);
        u64 ek = ((u64)__float_as_uint(dist) << 13) | (u64)(u32)c;
        best = ek < best ? ek : best;
    }
    if (lane == 0) {
        int c = (int)(best & 8191u);
        idxOut[gw] = c;
        out4[gw] = (float)c;
    }
}

// ---------------- Kernel C: gather + outputs + per-row loss partial ----------------
__global__ void vq_gather_kernel(const float* __restrict__ x,
                                 const float* __restrict__ cb,
                                 const int* __restrict__ idxArr,
                                 float* __restrict__ out0,
                                 float* __restrict__ out3,
                                 float* __restrict__ rowPart) {
    int gw = (blockIdx.x * blockDim.x + threadIdx.x) >> 6;
    int lane = threadIdx.x & 63;
    if (gw >= N_ROWS) return;
    int idx = idxArr[gw];
    const float2* xp = (const float2*)(x  + (size_t)gw * DIM);
    const float2* qp = (const float2*)(cb + (size_t)idx * DIM);
    float2* o0 = (float2*)(out0 + (size_t)gw * DIM);
    float2* o3 = (float2*)(out3 + (size_t)gw * DIM);
    float part = 0.0f;
    #pragma unroll
    for (int r = 0; r < 4; ++r) {
        int e = r * 64 + lane;
        float2 xv = xp[e];
        float2 qv = qp[e];
        float dx = qv.x - xv.x, dy = qv.y - xv.y;
        part += dx * dx + dy * dy;
        float2 o; o.x = xv.x + dx; o.y = xv.y + dy;
        o0[e] = o;
        o3[e] = qv;
    }
    #pragma unroll
    for (int m = 32; m; m >>= 1) part += __shfl_xor(part, m);
    if (lane == 0) rowPart[gw] = part;
}

// ---------------- Kernel D: deterministic loss reduce ----------------
__global__ void vq_loss_kernel(const float* __restrict__ rowPart,
                               float* __restrict__ out1, float* __restrict__ out2) {
    __shared__ float red[256];
    int t = threadIdx.x;
    float s = 0.0f;
    for (int r = t; r < N_ROWS; r += 256) s += rowPart[r];
    red[t] = s;
    __syncthreads();
    #pragma unroll
    for (int m = 128; m; m >>= 1) {
        if (t < m) red[t] += red[t + m];
        __syncthreads();
    }
    if (t == 0) {
        float loss = red[0] / (float)(N_ROWS * DIM);
        out1[0] = loss;
        out2[0] = loss;
    }
}

extern "C" void kernel_launch(void* const* d_in, const int* in_sizes, int n_in,
                              void* d_out, int out_size, void* d_ws, size_t ws_size,
                              hipStream_t stream) {
    const float* x  = (const float*)d_in[0];   // [16384, 512]
    const float* cb = (const float*)d_in[1];   // [8192, 512]
    float* out  = (float*)d_out;
    float* out0 = out;                         // quantized_out [8388608]
    float* out1 = out + 8388608;               // q_latent_loss [1]
    float* out2 = out + 8388609;               // e_latent_loss [1]
    float* out3 = out + 8388610;               // quantized [8388608]
    float* out4 = out + 16777218;              // idx as float [16384]

    // d_out doubles as split scratch until vq_gather overwrites it (stream-ordered).
    u16* xhi   = (u16*)out0;                       // [0, 4194304) floats
    u16* xmid  = (u16*)(out + 4194304);            // [4194304, 8388608)
    u16* cbhi  = (u16*)(out + 8388612);            // [8388612, 10485764)  16B-aligned
    u16* cbmid = (u16*)(out + 10485764);           // [10485764, 12582916)

    char* ws = (char*)d_ws;
    float* wsA    = (float*)ws;                        // 16384 f
    float* wsB    = (float*)(ws + 65536);              // 8192 f
    u64*   wsTop2 = (u64*)(ws + 98304);                // 4*16384*2 u64 = 1MB
    int*   wsIdx  = (int*)(ws + 98304 + 1048576);      // 16384 int
    float* wsPart = (float*)(ws + 98304 + 1048576 + 65536); // 16384 f

    hipLaunchKernelGGL(vq_split_kernel,   dim3(12288), dim3(256), 0, stream,
                       x, cb, xhi, xmid, cbhi, cbmid);
    hipLaunchKernelGGL(vq_np_norm_kernel, dim3(96), dim3(256), 0, stream, x, cb, wsA, wsB);
    hipLaunchKernelGGL(vq_screen_kernel,  dim3(N_ROWS / BM, SLICES), dim3(256), 0, stream,
                       xhi, xmid, cbhi, cbmid, wsA, wsB, wsTop2);
    hipLaunchKernelGGL(vq_refine_kernel,  dim3(4096), dim3(256), 0, stream,
                       x, cb, wsA, wsB, wsTop2, wsIdx, out4);
    hipLaunchKernelGGL(vq_gather_kernel,  dim3(4096), dim3(256), 0, stream,
                       x, cb, wsIdx, out0, out3, wsPart);
    hipLaunchKernelGGL(vq_loss_kernel,    dim3(1),   dim3(256), 0, stream,
                       wsPart, out1, out2);
}